// Round 7
// baseline (320.959 us; speedup 1.0000x reference)
//
#include <hip/hip_runtime.h>

// Sizes (fixed by the problem)
#define S_IN 256
#define IN_PER_BATCH (S_IN * S_IN * S_IN)
#define D1_PER_BATCH (128 * 128 * 128)
#define D2_PER_BATCH (64 * 64 * 64)
#define X_ELEMS (2 * IN_PER_BATCH)
#define D1_ELEMS (2 * D1_PER_BATCH)
#define D2_ELEMS (2 * D2_PER_BATCH)

// Staged tile: 8x8x32 core, +-2 halo (z,y), x staged [x0-4, x0+35]
// Row = 40 floats = 10 float4 -> LDS byte offset of vec v is exactly 16*v
#define LXR 40
#define NROW 144                 // 12 z * 12 y real rows
#define BUFV 1536                // padded to 6 full slots of 256 lanes (>= 1440)
#define BUFF (BUFV * 4)          // 6144 floats = 24 KB
#define NBLK 16384

__device__ __forceinline__ void gload_lds16(const float* g, float* l) {
    __builtin_amdgcn_global_load_lds(
        (const __attribute__((address_space(1))) void*)g,
        (__attribute__((address_space(3))) void*)l, 16, 0, 0);
}

__global__ __launch_bounds__(256, 6) void fused_pyramid(
    const float* __restrict__ x, const float* __restrict__ k0,
    const float* __restrict__ k1, float* __restrict__ out0,
    float* __restrict__ out1, float* __restrict__ out2)
{
    __shared__ float ls[BUFF];
    __shared__ float kw0[9][4];      // 3x3x3 weights, rows padded to 4
    __shared__ float kw1[25][8];     // 5x5x5 weights, rows padded to 8

    const int tid = threadIdx.x;
    if (tid < 27) kw0[tid / 3][tid % 3] = k0[tid];
    else if (tid >= 32 && tid < 157) {
        int t = tid - 32;
        kw1[t / 5][t % 5] = k1[t];
    }

    // XCD-contiguous swizzle: 16384 = 8 * 2048 (bijective). Same-XCD blocks
    // are consecutive in lin.
    // *** Ordering experiment (r7): dz is the FASTEST lin dimension so that
    // z-halo sharers (dz+-1) are 1 block apart -> staged z-halo planes are
    // still L2-resident when the neighbor re-stages them. y-sharers are 32
    // blocks apart (768 KB staged between, L2-hit). Only the x-halo (8/40
    // columns, sharers 1024 apart) still misses L2.
    const int bx  = blockIdx.x;
    const int lin = (bx & 7) * 2048 + (bx >> 3);
    const int dz = lin & 31;          // 32 z-tiles  (fastest)
    const int hy = (lin >> 5) & 31;   // 32 y-tiles
    const int wt = (lin >> 10) & 7;   // 8 x-tiles
    const int n  = lin >> 13;         // 2 batches

    const int x0 = wt << 5;
    const int y0 = hy << 3;
    const int z0 = dz << 3;
    const bool edge = (wt == 0);      // block-uniform

    const float* xb = x + (size_t)n * IN_PER_BATCH;

    // ---- issue all staging DMA (wave-uniform LDS base + lane*16) ----
    {
        float* lb = ls + (tid << 2);
#pragma unroll
        for (int i = 0; i < 6; ++i) {
            int v = tid + (i << 8);
            int row = v / 10;            // 10 float4 per LDS row
            int j = v - row * 10;
            int lz = row / 12;           // pad slots give lz up to 12 (clamped)
            int ly = row - lz * 12;
            int gz = z0 + lz - 2; gz = gz < 0 ? 0 : (gz > 255 ? 255 : gz);
            int gy = y0 + ly - 2; gy = gy < 0 ? 0 : (gy > 255 ? 255 : gy);
            int gx = x0 - 4 + (j << 2); gx = gx < 0 ? 0 : (gx > 252 ? 252 : gx);
            gload_lds16(xb + (((size_t)gz << 16) + (gy << 8) + gx),
                        lb + (size_t)i * 1024);
        }
    }

    // ---- left-edge patch value (wt==0 only): columns gx=-2,-1 -> x[...,0]
    float pv = 0.0f;
    int plz = 0, ply = 0;
    const bool pact = edge && (tid < NROW);
    if (pact) {
        plz = tid / 12;
        ply = tid - plz * 12;
        int gz = z0 + plz - 2; gz = gz < 0 ? 0 : (gz > 255 ? 255 : gz);
        int gy = y0 + ply - 2; gy = gy < 0 ? 0 : (gy > 255 ? 255 : gy);
        pv = xb[((size_t)gz << 16) + (gy << 8)];
    }

    __syncthreads();                   // drains vmcnt -> DMA landed
    if (edge) {
        if (pact)
            *reinterpret_cast<float2*>(
                &ls[(plz * 12 + ply) * LXR + 2]) = make_float2(pv, pv);
        __syncthreads();
    }

    // ---- 1) passthrough copy of the 8x8x32 core (LDS -> global, float4) ----
    {
        float* ob0 = out0 + (size_t)n * IN_PER_BATCH
                   + (((size_t)dz << 3) << 16) + (y0 << 8) + x0;
#pragma unroll
        for (int k = 0; k < 2; ++k) {
            int v = tid + (k << 8);      // 0..511 core float4s
            int jj = v & 7;
            int rowc = v >> 3;           // 0..63 (8z x 8y)
            int lzc = rowc >> 3, lyc = rowc & 7;
            float4 val = *reinterpret_cast<const float4*>(
                &ls[((lzc + 2) * 12 + (lyc + 2)) * LXR + 4 + (jj << 2)]);
            *reinterpret_cast<float4*>(
                &ob0[((size_t)lzc << 16) + (lyc << 8) + (jj << 2)]) = val;
        }
    }

    // ---- 2) d1: 3x3x3 stride-2 -> 4x4x16 outputs, 1 per thread ----
    {
        const int ox = tid & 15, oy = (tid >> 4) & 3, oz = tid >> 6;
        const float* base = ls + ((2 * oz + 1) * 12 + (2 * oy + 1)) * LXR + 2 * ox + 2;
        float acc = 0.0f;
#pragma unroll
        for (int a = 0; a < 3; ++a)
#pragma unroll
            for (int b = 0; b < 3; ++b) {
                const float* lr = base + (a * 12 + b) * LXR;
                float2 v0 = *reinterpret_cast<const float2*>(lr);
                float2 v1 = *reinterpret_cast<const float2*>(lr + 2);
                float4 kr = *reinterpret_cast<const float4*>(&kw0[a * 3 + b][0]);
                acc = fmaf(kr.x, v0.y, acc);
                acc = fmaf(kr.y, v1.x, acc);
                acc = fmaf(kr.z, v1.y, acc);
            }
        float* ob1 = out1 + (size_t)n * D1_PER_BATCH
                   + (((size_t)dz << 2) << 14) + ((hy << 2) << 7) + (wt << 4);
        ob1[(oz << 14) + (oy << 7) + ox] = acc;
    }

    // ---- 3) d2: 5x5x5 stride-4 -> 2x2x8 outputs, 8 threads/output ----
    {
        const int q = tid & 7;
        const int o = tid >> 3;
        const int ox = o & 7, oy = (o >> 3) & 1, oz = o >> 4;
        float acc = 0.0f;
#pragma unroll
        for (int m = 0; m < 4; ++m) {
            int r = q + (m << 3);
            if (r < 25) {
                int a = r / 5, b = r - 5 * a;
                const float* lr = ls + ((4 * oz + a) * 12 + (4 * oy + b)) * LXR + (ox << 2);
                float4 A4 = *reinterpret_cast<const float4*>(lr);
                float4 B4 = *reinterpret_cast<const float4*>(lr + 4);
                float4 kr = *reinterpret_cast<const float4*>(&kw1[r][0]);
                float k4 = kw1[r][4];
                acc = fmaf(kr.x, A4.z, acc);
                acc = fmaf(kr.y, A4.w, acc);
                acc = fmaf(kr.z, B4.x, acc);
                acc = fmaf(kr.w, B4.y, acc);
                acc = fmaf(k4,   B4.z, acc);
            }
        }
        acc += __shfl_xor(acc, 1);
        acc += __shfl_xor(acc, 2);
        acc += __shfl_xor(acc, 4);
        if (q == 0) {
            float* ob2 = out2 + (size_t)n * D2_PER_BATCH
                       + (((size_t)dz << 1) << 12) + ((hy << 1) << 6) + (wt << 3);
            ob2[(oz << 12) + (oy << 6) + ox] = acc;
        }
    }
}

extern "C" void kernel_launch(void* const* d_in, const int* in_sizes, int n_in,
                              void* d_out, int out_size, void* d_ws, size_t ws_size,
                              hipStream_t stream) {
    const float* x  = (const float*)d_in[0];
    const float* k0 = (const float*)d_in[1];   // 27 floats (3x3x3)
    const float* k1 = (const float*)d_in[2];   // 125 floats (5x5x5)

    float* out0 = (float*)d_out;               // x passthrough
    float* out1 = out0 + X_ELEMS;              // d1
    float* out2 = out1 + D1_ELEMS;             // d2

    fused_pyramid<<<NBLK, 256, 0, stream>>>(x, k0, k1, out0, out1, out2);
}